// Round 2
// baseline (109.015 us; speedup 1.0000x reference)
//
#include <hip/hip_runtime.h>

#define BB 2048          // batches
#define TT 4096          // timesteps
#define LN2 0.69314718055994530942f

constexpr int clog2(int x) { int l = 0; while ((1 << l) < x) ++l; return l; }

// Record layout (12 planes, b-major within each plane: idx = b*NC + c):
//  0..8  : 3x3 matrix (row-major), value = stored * 2^shift
//  9     : shift (int bits)
//  10    : score (emit + within-range transition scores)
//  11    : packed tags: firstTag | (lastTag << 8)

// ---------------------------------------------------------------------------
// Pass 1: thread = (batch b, chunk c). LLC = NG*16 timesteps per chunk.
// Round-2 changes vs previous:
//  * NEW NC=256 tier (LLC=16, NG=1) with __launch_bounds__(256,8): grid 2048
//    blocks -> 8 blocks/CU -> 32 waves/CU (2x TLP). VGPR cap 512/8 = 64 ==
//    measured VGPR_Count, so occupancy doubles without spilling.
//  * Transition score no longer does a dependent LDS read per step
//    (ds_read + lgkmcnt stall x32). Instead each (prev,tag) pair increments a
//    7-bit field in a 64-bit accumulator (9 pairs x 7 bits; max 127
//    transitions/chunk fits all tiers). Dot with sTrans once at the end.
// ---------------------------------------------------------------------------
template<int NG, int WPE>
__global__ __launch_bounds__(256, WPE) void crf_pass1(
    const float* __restrict__ logits, const float* __restrict__ trans,
    const int* __restrict__ tags, float* __restrict__ ws)
{
    constexpr int LLC = NG * 16;
    constexpr int NC  = TT / LLC;
    constexpr int LOGNC = clog2(NC);
    constexpr size_t CB = (size_t)NC * BB;

    __shared__ float sTrans[9];
    __shared__ float sTrExp[9];
    int tid = threadIdx.x;
    if (tid < 9) {
        float tv = trans[tid];
        sTrans[tid] = tv;
        sTrExp[tid] = __expf(tv);
    }
    __syncthreads();

    int w = blockIdx.x * 256 + tid;
    int c = w & (NC - 1);            // lane-contiguous chunk index
    int b = w >> LOGNC;              // wave/block-uniform batch
    const bool first_chunk = (c == 0);

    float t00 = sTrExp[0], t01 = sTrExp[1], t02 = sTrExp[2];
    float t10 = sTrExp[3], t11 = sTrExp[4], t12 = sTrExp[5];
    float t20 = sTrExp[6], t21 = sTrExp[7], t22 = sTrExp[8];

    float a00 = 1.f, a01 = 0.f, a02 = 0.f;
    float a10 = 0.f, a11 = 1.f, a12 = 0.f;
    float a20 = 0.f, a21 = 0.f, a22 = 1.f;
    int   se = 0;
    float score = 0.f;
    unsigned long long acc = 0ull;   // 9 x 7-bit transition-pair counters
    int firstTag = 0, prev = 0;

    const float4* lp = (const float4*)(logits + ((size_t)b * TT + (size_t)c * LLC) * 3);
    const int4*   tp = (const int4*)(tags + (size_t)b * TT + (size_t)c * LLC);

#define MATSTEP(e0_, e1_, e2_) do {                                     \
    float x0 = __expf(e0_), x1 = __expf(e1_), x2 = __expf(e2_);         \
    float b0 = (a00*t00 + a01*t10 + a02*t20) * x0;                      \
    float b1 = (a00*t01 + a01*t11 + a02*t21) * x1;                      \
    float b2 = (a00*t02 + a01*t12 + a02*t22) * x2;                      \
    float b3 = (a10*t00 + a11*t10 + a12*t20) * x0;                      \
    float b4 = (a10*t01 + a11*t11 + a12*t21) * x1;                      \
    float b5 = (a10*t02 + a11*t12 + a12*t22) * x2;                      \
    float b6 = (a20*t00 + a21*t10 + a22*t20) * x0;                      \
    float b7 = (a20*t01 + a21*t11 + a22*t21) * x1;                      \
    float b8 = (a20*t02 + a21*t12 + a22*t22) * x2;                      \
    a00=b0; a01=b1; a02=b2; a10=b3; a11=b4; a12=b5; a20=b6; a21=b7; a22=b8; \
} while (0)

#define RENORM do {                                                     \
    float m = fmaxf(fmaxf(fmaxf(a00, a01), fmaxf(a02, a10)),            \
                    fmaxf(fmaxf(a11, a12), fmaxf(fmaxf(a20, a21), a22))); \
    int ef = (int)(__float_as_uint(m) >> 23);                           \
    float scf = __uint_as_float((unsigned)(254 - ef) << 23);            \
    se += ef - 127;                                                     \
    a00 *= scf; a01 *= scf; a02 *= scf;                                 \
    a10 *= scf; a11 *= scf; a12 *= scf;                                 \
    a20 *= scf; a21 *= scf; a22 *= scf;                                 \
} while (0)

#pragma unroll
    for (int g = 0; g < NG; ++g) {
        // ---- load one 16-step clause (all constant-index -> registers) ----
        float Lf[48];
        int   Ti[16];
#pragma unroll
        for (int i = 0; i < 12; ++i) {
            float4 t = lp[g * 12 + i];
            Lf[4*i+0] = t.x; Lf[4*i+1] = t.y; Lf[4*i+2] = t.z; Lf[4*i+3] = t.w;
        }
#pragma unroll
        for (int i = 0; i < 4; ++i) {
            int4 t = tp[g * 4 + i];
            Ti[4*i+0] = t.x; Ti[4*i+1] = t.y; Ti[4*i+2] = t.z; Ti[4*i+3] = t.w;
        }
        // ---- 16 steps ----
#pragma unroll
        for (int s = 0; s < 16; ++s) {
            float e0 = Lf[3*s+0], e1 = Lf[3*s+1], e2 = Lf[3*s+2];
            int tg = Ti[s];
            if (g == 0 && s == 0) {
                if (!first_chunk) MATSTEP(e0, e1, e2);
                firstTag = tg;
            } else {
                MATSTEP(e0, e1, e2);
                acc += 1ull << (7 * (prev * 3 + tg));   // pure-VALU transition count
            }
            score += (tg == 0) ? e0 : ((tg == 1) ? e1 : e2);
            prev = tg;
            if ((s & 7) == 7) RENORM;
        }
    }

    // fold transition-pair counts into score (one-time LDS reads)
#pragma unroll
    for (int p = 0; p < 9; ++p)
        score += (float)((int)((acc >> (7 * p)) & 127ull)) * sTrans[p];

    size_t idx = (size_t)b * NC + c;          // b-major: lanes store contiguously
    ws[0*CB+idx] = a00; ws[1*CB+idx] = a01; ws[2*CB+idx] = a02;
    ws[3*CB+idx] = a10; ws[4*CB+idx] = a11; ws[5*CB+idx] = a12;
    ws[6*CB+idx] = a20; ws[7*CB+idx] = a21; ws[8*CB+idx] = a22;
    ((int*)ws)[9*CB+idx] = se;
    ws[10*CB+idx] = score;
    ((int*)ws)[11*CB+idx] = firstTag | (prev << 8);

#undef MATSTEP
#undef RENORM
}

// ---------------------------------------------------------------------------
// Pass 2a: thread = (batch b, super-chunk s). Folds 8 chunk records into one
// super-record. b-major layout: a lane's 8 records are CONTIGUOUS per plane,
// so each plane loads as 2x float4 (fully dense wave footprint).
// ---------------------------------------------------------------------------
__global__ __launch_bounds__(64) void crf_pass2a(
    const float* __restrict__ ws, float* __restrict__ ws2,
    const float* __restrict__ trans, int NC, int logNS)
{
    size_t CB  = (size_t)NC * BB;
    int NS = NC >> 3;
    size_t CB2 = (size_t)NS * BB;
    __shared__ float sTrans[9];
    if (threadIdx.x < 9) sTrans[threadIdx.x] = trans[threadIdx.x];
    __syncthreads();

    int u = blockIdx.x * 64 + threadIdx.x;
    int s = u & (NS - 1);            // lane-contiguous super-chunk
    int b = u >> logNS;

    size_t base = (size_t)b * NC + (size_t)s * 8;
    float M[12][8];
#pragma unroll
    for (int pl = 0; pl < 12; ++pl) {
        const float4* q = (const float4*)(ws + (size_t)pl * CB + base);
        float4 x = q[0], y = q[1];
        M[pl][0]=x.x; M[pl][1]=x.y; M[pl][2]=x.z; M[pl][3]=x.w;
        M[pl][4]=y.x; M[pl][5]=y.y; M[pl][6]=y.z; M[pl][7]=y.w;
    }

    float p00 = M[0][0], p01 = M[1][0], p02 = M[2][0];
    float p10 = M[3][0], p11 = M[4][0], p12 = M[5][0];
    float p20 = M[6][0], p21 = M[7][0], p22 = M[8][0];
    int   sh  = __float_as_int(M[9][0]);
    float score = M[10][0];
    int   pk  = __float_as_int(M[11][0]);
    int first0 = pk & 255, last = pk >> 8;

#pragma unroll
    for (int k = 1; k < 8; ++k) {
        float m00 = M[0][k], m01 = M[1][k], m02 = M[2][k];
        float m10 = M[3][k], m11 = M[4][k], m12 = M[5][k];
        float m20 = M[6][k], m21 = M[7][k], m22 = M[8][k];
        int   shm = __float_as_int(M[9][k]);
        float scm = M[10][k];
        int   pkm = __float_as_int(M[11][k]);

        float c00 = p00*m00 + p01*m10 + p02*m20;
        float c01 = p00*m01 + p01*m11 + p02*m21;
        float c02 = p00*m02 + p01*m12 + p02*m22;
        float c10 = p10*m00 + p11*m10 + p12*m20;
        float c11 = p10*m01 + p11*m11 + p12*m21;
        float c12 = p10*m02 + p11*m12 + p12*m22;
        float c20 = p20*m00 + p21*m10 + p22*m20;
        float c21 = p20*m01 + p21*m11 + p22*m21;
        float c22 = p20*m02 + p21*m12 + p22*m22;

        float mx = fmaxf(fmaxf(fmaxf(c00, c01), fmaxf(c02, c10)),
                         fmaxf(fmaxf(c11, c12), fmaxf(fmaxf(c20, c21), c22)));
        int ef = (int)(__float_as_uint(mx) >> 23);
        float scf = __uint_as_float((unsigned)(254 - ef) << 23);
        sh += shm + ef - 127;
        p00 = c00*scf; p01 = c01*scf; p02 = c02*scf;
        p10 = c10*scf; p11 = c11*scf; p12 = c12*scf;
        p20 = c20*scf; p21 = c21*scf; p22 = c22*scf;

        score += scm + sTrans[last * 3 + (pkm & 255)];
        last = pkm >> 8;
    }

    size_t o = (size_t)b * NS + s;   // b-major: lanes store contiguously
    ws2[0*CB2+o] = p00; ws2[1*CB2+o] = p01; ws2[2*CB2+o] = p02;
    ws2[3*CB2+o] = p10; ws2[4*CB2+o] = p11; ws2[5*CB2+o] = p12;
    ws2[6*CB2+o] = p20; ws2[7*CB2+o] = p21; ws2[8*CB2+o] = p22;
    ((int*)ws2)[9*CB2+o] = sh;
    ws2[10*CB2+o] = score;
    ((int*)ws2)[11*CB2+o] = first0 | (last << 8);
}

// ---------------------------------------------------------------------------
// Pass 2b: thread = batch. v = exp(logits[b,0,:]); fold NS super-records
// (b-major: a thread's records are contiguous -> float4 loads, 4 records
// per clause). nll = logz - score. Wave-reduce -> 32 partials.
// ---------------------------------------------------------------------------
template<int NS>
__global__ __launch_bounds__(64) void crf_pass2b(
    const float* __restrict__ logits, const float* __restrict__ ws2,
    const float* __restrict__ trans, float* __restrict__ partial)
{
    __shared__ float sTrans[9];
    if (threadIdx.x < 9) sTrans[threadIdx.x] = trans[threadIdx.x];
    __syncthreads();

    size_t CB2 = (size_t)NS * BB;
    int b = blockIdx.x * 64 + threadIdx.x;
    const float* lb = logits + (size_t)b * TT * 3;
    float v0 = __expf(lb[0]);
    float v1 = __expf(lb[1]);
    float v2 = __expf(lb[2]);
    int stot = 0; float score = 0.f; int last = 0;
    const size_t base = (size_t)b * NS;

#pragma unroll
    for (int sq = 0; sq < NS / 4; ++sq) {
        float Q[12][4];
#pragma unroll
        for (int pl = 0; pl < 12; ++pl) {
            float4 x = *(const float4*)(ws2 + (size_t)pl * CB2 + base + sq * 4);
            Q[pl][0] = x.x; Q[pl][1] = x.y; Q[pl][2] = x.z; Q[pl][3] = x.w;
        }
#pragma unroll
        for (int j = 0; j < 4; ++j) {
            int s = sq * 4 + j;
            float p00 = Q[0][j], p01 = Q[1][j], p02 = Q[2][j];
            float p10 = Q[3][j], p11 = Q[4][j], p12 = Q[5][j];
            float p20 = Q[6][j], p21 = Q[7][j], p22 = Q[8][j];
            int   sh  = __float_as_int(Q[9][j]);
            float sc  = Q[10][j];
            int   pk  = __float_as_int(Q[11][j]);

            score += sc;
            if (s > 0) score += sTrans[last * 3 + (pk & 255)];
            last = pk >> 8;

            float n0 = v0*p00 + v1*p10 + v2*p20;
            float n1 = v0*p01 + v1*p11 + v2*p21;
            float n2 = v0*p02 + v1*p12 + v2*p22;
            stot += sh;
            float mx = fmaxf(fmaxf(n0, n1), n2);
            int ef = (int)(__float_as_uint(mx) >> 23);
            float scf = __uint_as_float((unsigned)(254 - ef) << 23);
            stot += ef - 127;
            v0 = n0*scf; v1 = n1*scf; v2 = n2*scf;
        }
    }

    float logz = logf(v0 + v1 + v2) + (float)stot * LN2;
    float nll = logz - score;

    for (int off = 32; off > 0; off >>= 1) nll += __shfl_down(nll, off, 64);
    if (threadIdx.x == 0) partial[blockIdx.x] = nll;
}

__global__ __launch_bounds__(64) void crf_pass3(
    const float* __restrict__ partial, float* __restrict__ out)
{
    float v = (threadIdx.x < 32) ? partial[threadIdx.x] : 0.f;
    for (int off = 32; off > 0; off >>= 1) v += __shfl_down(v, off, 64);
    if (threadIdx.x == 0) out[0] = v;
}

extern "C" void kernel_launch(void* const* d_in, const int* in_sizes, int n_in,
                              void* d_out, int out_size, void* d_ws, size_t ws_size,
                              hipStream_t stream) {
    const float* logits = (const float*)d_in[0];
    const float* trans  = (const float*)d_in[1];
    const int*   tags   = (const int*)d_in[2];
    float* out = (float*)d_out;
    float* ws  = (float*)d_ws;

    auto need = [](int NC) -> size_t {
        return (size_t)12 * NC * BB * 4 + (size_t)12 * (NC/8) * BB * 4 + 256;
    };
    int NC;
    if      (ws_size >= need(256)) NC = 256;
    else if (ws_size >= need(128)) NC = 128;
    else if (ws_size >= need(64))  NC = 64;
    else                           NC = 32;

    float* ws2     = ws + (size_t)12 * NC * BB;
    float* partial = ws2 + (size_t)12 * (NC/8) * BB;
    int NS = NC / 8;
    int logNS = __builtin_ctz(NS);

    int blocks1 = NC * BB / 256;
    if (NC == 256)      crf_pass1<1, 8><<<dim3(blocks1), dim3(256), 0, stream>>>(logits, trans, tags, ws);
    else if (NC == 128) crf_pass1<2, 4><<<dim3(blocks1), dim3(256), 0, stream>>>(logits, trans, tags, ws);
    else if (NC == 64)  crf_pass1<4, 4><<<dim3(blocks1), dim3(256), 0, stream>>>(logits, trans, tags, ws);
    else                crf_pass1<8, 4><<<dim3(blocks1), dim3(256), 0, stream>>>(logits, trans, tags, ws);

    crf_pass2a<<<dim3(NS * BB / 64), dim3(64), 0, stream>>>(ws, ws2, trans, NC, logNS);

    if (NC == 256)      crf_pass2b<32><<<dim3(32), dim3(64), 0, stream>>>(logits, ws2, trans, partial);
    else if (NC == 128) crf_pass2b<16><<<dim3(32), dim3(64), 0, stream>>>(logits, ws2, trans, partial);
    else if (NC == 64)  crf_pass2b<8><<<dim3(32), dim3(64), 0, stream>>>(logits, ws2, trans, partial);
    else                crf_pass2b<4><<<dim3(32), dim3(64), 0, stream>>>(logits, ws2, trans, partial);

    crf_pass3<<<dim3(1), dim3(64), 0, stream>>>(partial, out);
}

// Round 3
// 31.463 us; speedup vs baseline: 3.4648x; 3.4648x over previous
//
#include <hip/hip_runtime.h>

#define BB 2048          // batches
#define TT 4096          // timesteps
#define LN2 0.69314718055994530942f

// ---------------------------------------------------------------------------
// Round-3 architecture: ONE kernel does the whole per-batch CRF fold.
//   * block = one batch row (256 threads x 16 timesteps = 4096).
//   * per-thread: straight-line 16-step exp-domain chunk product
//     (12 float4 + 4 int4 loads, sched_barrier after loads so the FULL
//     clause is issued before compute -> ~16KB outstanding per wave).
//   * in-wave ORDER-PRESERVING shfl_xor butterfly folds 64 chunk matrices
//     (at mask m the lower lane's matrix multiplies on the left; inductively
//     every lane holds the ordered product of its aligned 2m-block).
//   * 4 wave records fold via LDS; thread 0 (whose clause contains t=0,
//     so it holds v = exp(logits[b,0,:])) computes nll = logz - score and
//     writes ONE float per batch. No 25MB workspace round-trip.
// Traffic: read 134 MB, write 8 KB  ->  ~21 us floor at 6.3 TB/s.
// ---------------------------------------------------------------------------
__global__ __launch_bounds__(256, 4) void crf_pass1(
    const float* __restrict__ logits, const float* __restrict__ trans,
    const int* __restrict__ tags, float* __restrict__ ws)
{
    __shared__ float sTrans[9];
    __shared__ float sTrExp[9];
    __shared__ float sRec[3][12];      // records of waves 1..3
    const int tid = threadIdx.x;
    if (tid < 9) {
        float tv = trans[tid];
        sTrans[tid] = tv;
        sTrExp[tid] = __expf(tv);
    }
    __syncthreads();

    const int b = blockIdx.x;
    const int c = tid;                 // chunk index = thread index

    float t00 = sTrExp[0], t01 = sTrExp[1], t02 = sTrExp[2];
    float t10 = sTrExp[3], t11 = sTrExp[4], t12 = sTrExp[5];
    float t20 = sTrExp[6], t21 = sTrExp[7], t22 = sTrExp[8];

    float a00 = 1.f, a01 = 0.f, a02 = 0.f;
    float a10 = 0.f, a11 = 1.f, a12 = 0.f;
    float a20 = 0.f, a21 = 0.f, a22 = 1.f;
    int   se = 0;
    float score = 0.f;
    unsigned long long acc = 0ull;     // 9 x 7-bit transition-pair counters
    int firstTag = 0, prev = 0;
    float v0 = 0.f, v1 = 0.f, v2 = 0.f;   // alpha0 (thread 0 only)

    const float4* lp = (const float4*)(logits + ((size_t)b * TT + (size_t)c * 16) * 3);
    const int4*   tp = (const int4*)(tags + (size_t)b * TT + (size_t)c * 16);

    // ---- issue the ENTIRE clause before any compute ----
    float Lf[48];
    int   Ti[16];
#pragma unroll
    for (int i = 0; i < 12; ++i) {
        float4 t = lp[i];
        Lf[4*i+0] = t.x; Lf[4*i+1] = t.y; Lf[4*i+2] = t.z; Lf[4*i+3] = t.w;
    }
#pragma unroll
    for (int i = 0; i < 4; ++i) {
        int4 t = tp[i];
        Ti[4*i+0] = t.x; Ti[4*i+1] = t.y; Ti[4*i+2] = t.z; Ti[4*i+3] = t.w;
    }
    __builtin_amdgcn_sched_barrier(0);   // all 16 loads issued; no strip-mining

#define MATSTEP(e0_, e1_, e2_) do {                                     \
    float x0 = __expf(e0_), x1 = __expf(e1_), x2 = __expf(e2_);         \
    float b0 = (a00*t00 + a01*t10 + a02*t20) * x0;                      \
    float b1 = (a00*t01 + a01*t11 + a02*t21) * x1;                      \
    float b2 = (a00*t02 + a01*t12 + a02*t22) * x2;                      \
    float b3 = (a10*t00 + a11*t10 + a12*t20) * x0;                      \
    float b4 = (a10*t01 + a11*t11 + a12*t21) * x1;                      \
    float b5 = (a10*t02 + a11*t12 + a12*t22) * x2;                      \
    float b6 = (a20*t00 + a21*t10 + a22*t20) * x0;                      \
    float b7 = (a20*t01 + a21*t11 + a22*t21) * x1;                      \
    float b8 = (a20*t02 + a21*t12 + a22*t22) * x2;                      \
    a00=b0; a01=b1; a02=b2; a10=b3; a11=b4; a12=b5; a20=b6; a21=b7; a22=b8; \
} while (0)

#define RENORM9(q00,q01,q02,q10,q11,q12,q20,q21,q22) do {               \
    float m_ = fmaxf(fmaxf(fmaxf(q00, q01), fmaxf(q02, q10)),           \
                     fmaxf(fmaxf(q11, q12), fmaxf(fmaxf(q20, q21), q22))); \
    int ef_ = (int)(__float_as_uint(m_) >> 23);                         \
    float scf_ = __uint_as_float((unsigned)(254 - ef_) << 23);          \
    se += ef_ - 127;                                                    \
    q00 *= scf_; q01 *= scf_; q02 *= scf_;                              \
    q10 *= scf_; q11 *= scf_; q12 *= scf_;                              \
    q20 *= scf_; q21 *= scf_; q22 *= scf_;                              \
} while (0)

    // ---- 16 steps ----
#pragma unroll
    for (int s = 0; s < 16; ++s) {
        float e0 = Lf[3*s+0], e1 = Lf[3*s+1], e2 = Lf[3*s+2];
        int tg = Ti[s];
        if (s == 0) {
            if (c == 0) {              // t=0: alpha0, no transition step
                v0 = __expf(e0); v1 = __expf(e1); v2 = __expf(e2);
            } else {
                MATSTEP(e0, e1, e2);
            }
            firstTag = tg;
        } else {
            MATSTEP(e0, e1, e2);
            acc += 1ull << (7 * (prev * 3 + tg));   // pure-VALU transition count
        }
        score += (tg == 0) ? e0 : ((tg == 1) ? e1 : e2);
        prev = tg;
        if ((s & 7) == 7) RENORM9(a00,a01,a02,a10,a11,a12,a20,a21,a22);
    }

    // fold transition-pair counts into score (max count 15 < 127)
#pragma unroll
    for (int p = 0; p < 9; ++p)
        score += (float)((int)((acc >> (7 * p)) & 127ull)) * sTrans[p];

    // ---- in-wave ordered butterfly fold of 64 chunk records ----
    const int lane = tid & 63;
#pragma unroll
    for (int m = 1; m < 64; m <<= 1) {
        float o00 = __shfl_xor(a00, m, 64), o01 = __shfl_xor(a01, m, 64), o02 = __shfl_xor(a02, m, 64);
        float o10 = __shfl_xor(a10, m, 64), o11 = __shfl_xor(a11, m, 64), o12 = __shfl_xor(a12, m, 64);
        float o20 = __shfl_xor(a20, m, 64), o21 = __shfl_xor(a21, m, 64), o22 = __shfl_xor(a22, m, 64);
        int   osh = __shfl_xor(se, m, 64);
        float osc = __shfl_xor(score, m, 64);
        int   ofi = __shfl_xor(firstTag, m, 64);
        int   ola = __shfl_xor(prev, m, 64);
        bool low = (lane & m) == 0;    // self is the LEFT (earlier) operand?
        float l00 = low ? a00 : o00, l01 = low ? a01 : o01, l02 = low ? a02 : o02;
        float l10 = low ? a10 : o10, l11 = low ? a11 : o11, l12 = low ? a12 : o12;
        float l20 = low ? a20 : o20, l21 = low ? a21 : o21, l22 = low ? a22 : o22;
        float r00 = low ? o00 : a00, r01 = low ? o01 : a01, r02 = low ? o02 : a02;
        float r10 = low ? o10 : a10, r11 = low ? o11 : a11, r12 = low ? o12 : a12;
        float r20 = low ? o20 : a20, r21 = low ? o21 : a21, r22 = low ? o22 : a22;

        float c00 = l00*r00 + l01*r10 + l02*r20;
        float c01 = l00*r01 + l01*r11 + l02*r21;
        float c02 = l00*r02 + l01*r12 + l02*r22;
        float c10 = l10*r00 + l11*r10 + l12*r20;
        float c11 = l10*r01 + l11*r11 + l12*r21;
        float c12 = l10*r02 + l11*r12 + l12*r22;
        float c20 = l20*r00 + l21*r10 + l22*r20;
        float c21 = l20*r01 + l21*r11 + l22*r21;
        float c22 = l20*r02 + l21*r12 + l22*r22;

        int Ll = low ? prev : ola;     // left block's last tag
        int Rf = low ? ofi : firstTag; // right block's first tag
        score = score + osc + sTrans[Ll * 3 + Rf];
        se += osh;
        firstTag = low ? firstTag : ofi;
        prev = low ? ola : prev;

        a00=c00; a01=c01; a02=c02; a10=c10; a11=c11; a12=c12; a20=c20; a21=c21; a22=c22;
        RENORM9(a00,a01,a02,a10,a11,a12,a20,a21,a22);
    }

    // ---- cross-wave fold (waves are time-ordered) ----
    const int wid = tid >> 6;
    if (lane == 0 && wid > 0) {
        sRec[wid-1][0] = a00; sRec[wid-1][1] = a01; sRec[wid-1][2] = a02;
        sRec[wid-1][3] = a10; sRec[wid-1][4] = a11; sRec[wid-1][5] = a12;
        sRec[wid-1][6] = a20; sRec[wid-1][7] = a21; sRec[wid-1][8] = a22;
        sRec[wid-1][9]  = __int_as_float(se);
        sRec[wid-1][10] = score;
        sRec[wid-1][11] = __int_as_float(firstTag | (prev << 8));
    }
    __syncthreads();
    if (tid == 0) {
#pragma unroll
        for (int k = 0; k < 3; ++k) {
            float m00 = sRec[k][0], m01 = sRec[k][1], m02 = sRec[k][2];
            float m10 = sRec[k][3], m11 = sRec[k][4], m12 = sRec[k][5];
            float m20 = sRec[k][6], m21 = sRec[k][7], m22 = sRec[k][8];
            int   shm = __float_as_int(sRec[k][9]);
            float scm = sRec[k][10];
            int   pkm = __float_as_int(sRec[k][11]);

            float c00 = a00*m00 + a01*m10 + a02*m20;
            float c01 = a00*m01 + a01*m11 + a02*m21;
            float c02 = a00*m02 + a01*m12 + a02*m22;
            float c10 = a10*m00 + a11*m10 + a12*m20;
            float c11 = a10*m01 + a11*m11 + a12*m21;
            float c12 = a10*m02 + a11*m12 + a12*m22;
            float c20 = a20*m00 + a21*m10 + a22*m20;
            float c21 = a20*m01 + a21*m11 + a22*m21;
            float c22 = a20*m02 + a21*m12 + a22*m22;

            score += scm + sTrans[prev * 3 + (pkm & 255)];
            prev = pkm >> 8;
            se += shm;
            a00=c00; a01=c01; a02=c02; a10=c10; a11=c11; a12=c12; a20=c20; a21=c21; a22=c22;
            RENORM9(a00,a01,a02,a10,a11,a12,a20,a21,a22);
        }
        // alpha_T = v . P  (row-vector times total product), true value * 2^se
        float n0 = v0*a00 + v1*a10 + v2*a20;
        float n1 = v0*a01 + v1*a11 + v2*a21;
        float n2 = v0*a02 + v1*a12 + v2*a22;
        float logz = logf(n0 + n1 + n2) + (float)se * LN2;
        ws[b] = logz - score;          // per-batch nll
    }

#undef MATSTEP
#undef RENORM9
}

// ---------------------------------------------------------------------------
// Final reduction: one block sums the 2048 per-batch nll values.
// ---------------------------------------------------------------------------
__global__ __launch_bounds__(256) void crf_reduce(
    const float* __restrict__ ws, float* __restrict__ out)
{
    int tid = threadIdx.x;
    float s = 0.f;
#pragma unroll
    for (int k = 0; k < BB / 256; ++k) s += ws[k * 256 + tid];
    for (int off = 32; off > 0; off >>= 1) s += __shfl_down(s, off, 64);
    __shared__ float sP[4];
    if ((tid & 63) == 0) sP[tid >> 6] = s;
    __syncthreads();
    if (tid == 0) out[0] = sP[0] + sP[1] + sP[2] + sP[3];
}

extern "C" void kernel_launch(void* const* d_in, const int* in_sizes, int n_in,
                              void* d_out, int out_size, void* d_ws, size_t ws_size,
                              hipStream_t stream) {
    const float* logits = (const float*)d_in[0];
    const float* trans  = (const float*)d_in[1];
    const int*   tags   = (const int*)d_in[2];
    float* out = (float*)d_out;
    float* ws  = (float*)d_ws;

    crf_pass1<<<dim3(BB), dim3(256), 0, stream>>>(logits, trans, tags, ws);
    crf_reduce<<<dim3(1), dim3(256), 0, stream>>>(ws, out);
}